// Round 1
// baseline (1060.362 us; speedup 1.0000x reference)
//
#include <hip/hip_runtime.h>
#include <math.h>

// ---------------------------------------------------------------------------
// Problem constants: B=16, T=4096, D=256, V=256, PATCH=4, Np=1024, BN=16384
// All GEMMs are NT with K=256: C[M,N] = A[M,256] @ Bt[N,256]^T (+epilogue)
// ---------------------------------------------------------------------------

typedef __bf16 bf16_t;
typedef bf16_t bf16x8 __attribute__((ext_vector_type(8)));
typedef float f32x4 __attribute__((ext_vector_type(4)));

#define GF_BIAS 1
#define GF_ACC 2
#define GF_GELU 4
#define GF_RES 8
#define GF_SCAUSAL 16

__device__ __forceinline__ float gelu_exact(float x) {
  return 0.5f * x * (1.0f + erff(x * 0.7071067811865475f));
}

__device__ __forceinline__ bf16x8 pack8(float4 a, float4 b) {
  bf16x8 r;
  r[0] = (bf16_t)a.x; r[1] = (bf16_t)a.y; r[2] = (bf16_t)a.z; r[3] = (bf16_t)a.w;
  r[4] = (bf16_t)b.x; r[5] = (bf16_t)b.y; r[6] = (bf16_t)b.z; r[7] = (bf16_t)b.w;
  return r;
}

// ---------------- generic bf16 MFMA GEMM (128x128 tile, 4 waves) ------------
template<int FLAGS>
__global__ __launch_bounds__(256)
void gemm_nt(const float* __restrict__ A, const float* __restrict__ Bt,
             float* __restrict__ C, const float* __restrict__ bias,
             const float* __restrict__ res, int M, int N,
             long long sA, long long sB, long long sC, float scale)
{
  (void)M;
  __shared__ __align__(16) bf16_t As[128][32];
  __shared__ __align__(16) bf16_t Bs[128][32];
  const int z = blockIdx.z;
  A  += (long long)z * sA;
  Bt += (long long)z * sB;
  C  += (long long)z * sC;
  const int m0 = blockIdx.x * 128, n0 = blockIdx.y * 128;
  if (FLAGS & GF_SCAUSAL) { if (n0 > m0 + 127) return; }  // fully-masked block
  const int tid  = threadIdx.x;
  const int lane = tid & 63, wave = tid >> 6;
  const int wm = (wave >> 1) << 6, wn = (wave & 1) << 6;
  const int lr = lane & 15, lg = lane >> 4;
  const int srow = tid >> 1, scol = (tid & 1) << 4;

  f32x4 acc[4][4] = {};

  const float* ap = A  + (long long)(m0 + srow) * 256 + scol;
  const float* bp = Bt + (long long)(n0 + srow) * 256 + scol;

  for (int kt = 0; kt < 256; kt += 32) {
    float4 a0 = *(const float4*)(ap + kt);
    float4 a1 = *(const float4*)(ap + kt + 4);
    float4 a2 = *(const float4*)(ap + kt + 8);
    float4 a3 = *(const float4*)(ap + kt + 12);
    float4 b0 = *(const float4*)(bp + kt);
    float4 b1 = *(const float4*)(bp + kt + 4);
    float4 b2 = *(const float4*)(bp + kt + 8);
    float4 b3 = *(const float4*)(bp + kt + 12);
    __syncthreads();
    *(bf16x8*)&As[srow][scol]     = pack8(a0, a1);
    *(bf16x8*)&As[srow][scol + 8] = pack8(a2, a3);
    *(bf16x8*)&Bs[srow][scol]     = pack8(b0, b1);
    *(bf16x8*)&Bs[srow][scol + 8] = pack8(b2, b3);
    __syncthreads();
    bf16x8 af[4], bfv[4];
#pragma unroll
    for (int i = 0; i < 4; i++) af[i]  = *(const bf16x8*)&As[wm + i*16 + lr][lg*8];
#pragma unroll
    for (int j = 0; j < 4; j++) bfv[j] = *(const bf16x8*)&Bs[wn + j*16 + lr][lg*8];
#pragma unroll
    for (int i = 0; i < 4; i++)
#pragma unroll
      for (int j = 0; j < 4; j++)
        acc[i][j] = __builtin_amdgcn_mfma_f32_16x16x32_bf16(af[i], bfv[j], acc[i][j], 0, 0, 0);
  }

#pragma unroll
  for (int i = 0; i < 4; i++) {
#pragma unroll
    for (int j = 0; j < 4; j++) {
      const int col = n0 + wn + j*16 + lr;
#pragma unroll
      for (int e = 0; e < 4; e++) {
        const int row = m0 + wm + i*16 + lg*4 + e;
        const long long ci = (long long)row * N + col;
        float v = acc[i][j][e];
        if (FLAGS & GF_SCAUSAL) { v *= scale; if (col > row) v = -__builtin_inff(); }
        if (FLAGS & GF_BIAS) v += bias[col];
        if (FLAGS & GF_ACC)  v += C[ci];
        if (FLAGS & GF_RES)  v += res[ci];
        if (FLAGS & GF_GELU) v = gelu_exact(v);
        C[ci] = v;
      }
    }
  }
}

// ---------------- weight transposes (f32 [K,N] -> f32 [N,K=256]) ------------
struct TransDesc { const float* src; float* dst; int N; int k0; int ld; };
struct TransArgs { TransDesc d[15]; };

__global__ __launch_bounds__(256) void k_transpose(TransArgs ta) {
  TransDesc t = ta.d[blockIdx.y];
  int i = blockIdx.x * 256 + threadIdx.x;
  if (i >= t.N * 256) return;
  int n = i >> 8, k = i & 255;
  t.dst[i] = t.src[(long long)(t.k0 + k) * t.ld + n];
}

// xe[p*256+v][d] = emb[v][d] + pos[p][d]
__global__ __launch_bounds__(256) void k_xe(const float* __restrict__ emb,
                                            const float* __restrict__ pos,
                                            float* __restrict__ xe) {
  int r = blockIdx.x, d = threadIdx.x;
  int p = r >> 8, v = r & 255;
  xe[(long long)r * 256 + d] = emb[v * 256 + d] + pos[p * 256 + d];
}

// ---------------- GRU gate (gi from table; gh from GEMM or bhh) -------------
__global__ __launch_bounds__(256)
void k_gru_gate(const int* __restrict__ x, const float* __restrict__ gitab,
                const float* __restrict__ GH, const float* __restrict__ bhh,
                float* __restrict__ H, float* __restrict__ LOC, int t)
{
  int s = blockIdx.x, d = threadIdx.x;
  int v = x[s * 4 + t];
  const float* gi = gitab + (long long)(t * 256 + v) * 768;
  float ir = gi[d], iz = gi[256 + d], inn = gi[512 + d];
  float hr, hz, hn, hprev;
  if (t == 0) { hr = bhh[d]; hz = bhh[256 + d]; hn = bhh[512 + d]; hprev = 0.f; }
  else {
    const float* gh = GH + (long long)s * 768;
    hr = gh[d]; hz = gh[256 + d]; hn = gh[512 + d];
    hprev = H[(long long)s * 256 + d];
  }
  float r  = 1.f / (1.f + expf(-(ir + hr)));
  float zz = 1.f / (1.f + expf(-(iz + hz)));
  float n  = tanhf(inn + r * hn);
  float h  = (1.f - zz) * n + zz * hprev;
  H[(long long)s * 256 + d] = h;
  LOC[((long long)s * 4 + t) * 256 + d] = h;
}

// ---------------- LayerNorm over D=256 (one block per row) ------------------
// addmode: 0 none, 1 add same-row, 2 add row>>2
__global__ __launch_bounds__(256)
void k_ln(const float* __restrict__ X, const float* __restrict__ ADD, int addmode,
          float* __restrict__ OUT, const float* __restrict__ g,
          const float* __restrict__ b)
{
  long long r = blockIdx.x;
  int d = threadIdx.x;
  __shared__ float sh[8];
  float x = X[r * 256 + d];
  if (addmode == 1)      x += ADD[r * 256 + d];
  else if (addmode == 2) x += ADD[(r >> 2) * 256 + d];
  float v = x;
#pragma unroll
  for (int o = 32; o; o >>= 1) v += __shfl_xor(v, o, 64);
  if ((d & 63) == 0) sh[d >> 6] = v;
  __syncthreads();
  float mean = (sh[0] + sh[1] + sh[2] + sh[3]) * (1.f / 256.f);
  float dx = x - mean;
  float q = dx * dx;
#pragma unroll
  for (int o = 32; o; o >>= 1) q += __shfl_xor(q, o, 64);
  if ((d & 63) == 0) sh[4 + (d >> 6)] = q;
  __syncthreads();
  float var = (sh[4] + sh[5] + sh[6] + sh[7]) * (1.f / 256.f);
  float rstd = rsqrtf(var + 1e-5f);
  OUT[r * 256 + d] = dx * rstd * g[d] + b[d];
}

// summ_in[s][d] = mean over t of LOC[s*4+t][d]
__global__ __launch_bounds__(256)
void k_summ4(const float* __restrict__ LOC, float* __restrict__ S) {
  long long i = (long long)blockIdx.x * 256 + threadIdx.x;
  long long s = i >> 8;
  int d = i & 255;
  const float* p = LOC + s * 1024 + d;
  S[i] = 0.25f * (p[0] + p[256] + p[512] + p[768]);
}

// g[s][d] = (1/5) sum_{w=0..4} gelu(a[s][d] + (n>=w ? bn[s-w][d] : 0))
__global__ __launch_bounds__(256)
void k_gelumix(const float* __restrict__ A, const float* __restrict__ BN,
               float* __restrict__ G) {
  long long i = (long long)blockIdx.x * 256 + threadIdx.x;
  long long s = i >> 8;
  int n = (int)(s & 1023);
  float a = A[i];
  const float* bp = BN + i;
  float acc = gelu_exact(a + bp[0]);                       // w=0 (self index)
  acc += gelu_exact(a + (n >= 1 ? bp[-256]  : 0.f));
  acc += gelu_exact(a + (n >= 2 ? bp[-512]  : 0.f));
  acc += gelu_exact(a + (n >= 3 ? bp[-768]  : 0.f));
  acc += gelu_exact(a + (n >= 4 ? bp[-1024] : 0.f));
  G[i] = acc * 0.2f;
}

// hp[b] = sigmoid( (mean_n h[b,n,:]) . halt_w + halt_b )
__global__ __launch_bounds__(256)
void k_halt(const float* __restrict__ Hm, const float* __restrict__ hw,
            const float* __restrict__ hb, float* __restrict__ HP) {
  int b = blockIdx.x, d = threadIdx.x;
  __shared__ float sh[4];
  const float* p = Hm + ((long long)b << 10) * 256 + d;
  float sum = 0.f;
  for (int n = 0; n < 1024; n++) sum += p[(long long)n * 256];
  float val = (sum * (1.f / 1024.f)) * hw[d];
#pragma unroll
  for (int o = 32; o; o >>= 1) val += __shfl_xor(val, o, 64);
  if ((d & 63) == 0) sh[d >> 6] = val;
  __syncthreads();
  if (d == 0) {
    float dot = sh[0] + sh[1] + sh[2] + sh[3] + hb[0];
    HP[b] = 1.f / (1.f + expf(-dot));
  }
}

// kl scalar (steps 0,1,3 are constants; step2 uses mean_b hp[b])
__global__ void k_kl(const float* __restrict__ HP, float* __restrict__ out) {
  float s = 0.f;
  for (int b = 0; b < 16; b++) s += HP[b];
  float hpm = s * (1.f / 16.f);
  float l8 = logf(1e-8f);
  float p0 = 0.2f, p1 = 0.16f, p2 = 0.128f, p3 = 0.1024f;
  float kl = p0 * (logf(p0) - l8)
           + p1 * (logf(p1) - l8)
           + p2 * (logf(p2) - logf(hpm + 1e-8f))
           + p3 * (logf(p3) - logf(1.f + 1e-8f));
  out[0] = kl * 0.25f;
}

// out_mp accumulation: acc=0 -> O = hp[b]*h ; acc=1 -> O += (1-hp[b])*h
__global__ __launch_bounds__(256)
void k_outmp(const float* __restrict__ Hm, const float* __restrict__ HP,
             float* __restrict__ O, int acc) {
  long long i = (long long)blockIdx.x * 256 + threadIdx.x;
  int b = (int)(i >> 18);
  if (acc) O[i] += (1.f - HP[b]) * Hm[i];
  else     O[i] = HP[b] * Hm[i];
}

// ---------------- top-8 causal sparse attention (1 wave per row) ------------
__global__ __launch_bounds__(64)
void k_topk(const float* __restrict__ S, const float* __restrict__ V,
            float* __restrict__ O) {
  const int n = blockIdx.x, b = blockIdx.y, lane = threadIdx.x;
  const float* srow = S + ((long long)(b * 1024 + n)) * 1024;
  float tv[8]; int ti[8];
#pragma unroll
  for (int j = 0; j < 8; j++) { tv[j] = -__builtin_inff(); ti[j] = 0x7fffffff; }
  for (int m = lane; m <= n; m += 64) {
    float s = srow[m];
    if (s > tv[7] || (s == tv[7] && m < ti[7])) {
      tv[7] = s; ti[7] = m;
#pragma unroll
      for (int j = 7; j > 0; j--) {
        bool sw = (tv[j] > tv[j-1]) || (tv[j] == tv[j-1] && ti[j] < ti[j-1]);
        if (sw) {
          float tf = tv[j]; tv[j] = tv[j-1]; tv[j-1] = tf;
          int   tt = ti[j]; ti[j] = ti[j-1]; ti[j-1] = tt;
        }
      }
    }
  }
  // wave-merge: 8 rounds of argmax over lane heads (tie -> lower index)
  float outv[8]; int outi[8];
#pragma unroll
  for (int r = 0; r < 8; r++) {
    float bv = tv[0]; int bi = ti[0]; int bl = lane;
    for (int off = 32; off; off >>= 1) {
      float ov = __shfl_xor(bv, off, 64);
      int   oi = __shfl_xor(bi, off, 64);
      int   ol = __shfl_xor(bl, off, 64);
      if (ov > bv || (ov == bv && oi < bi)) { bv = ov; bi = oi; bl = ol; }
    }
    outv[r] = bv; outi[r] = bi;
    if (lane == bl) {
      tv[0]=tv[1]; ti[0]=ti[1]; tv[1]=tv[2]; ti[1]=ti[2]; tv[2]=tv[3]; ti[2]=ti[3];
      tv[3]=tv[4]; ti[3]=ti[4]; tv[4]=tv[5]; ti[4]=ti[5]; tv[5]=tv[6]; ti[5]=ti[6];
      tv[6]=tv[7]; ti[6]=ti[7]; tv[7] = -__builtin_inff(); ti[7] = 0x7fffffff;
    }
  }
  // softmax over selected (outv[0] is max), then gather V rows
  float mx = outv[0];
  float w[8]; float den = 0.f;
#pragma unroll
  for (int j = 0; j < 8; j++) {
    w[j] = (outv[j] > -__builtin_inff()) ? expf(outv[j] - mx) : 0.f;
    den += w[j];
  }
  float inv = 1.f / den;
  const float* vb = V + ((long long)b * 1024) * 256;
  float ax = 0.f, ay = 0.f, az = 0.f, aw = 0.f;
#pragma unroll
  for (int j = 0; j < 8; j++) {
    if (outv[j] > -__builtin_inff()) {
      const float4 vv = *(const float4*)(vb + (long long)outi[j] * 256 + lane * 4);
      float wj = w[j] * inv;
      ax = fmaf(wj, vv.x, ax); ay = fmaf(wj, vv.y, ay);
      az = fmaf(wj, vv.z, az); aw = fmaf(wj, vv.w, aw);
    }
  }
  float4 o4; o4.x = ax; o4.y = ay; o4.z = az; o4.w = aw;
  *(float4*)(O + ((long long)(b * 1024 + n)) * 256 + lane * 4) = o4;
}

// ---------------------------------------------------------------------------
extern "C" void kernel_launch(void* const* d_in, const int* in_sizes, int n_in,
                              void* d_out, int out_size, void* d_ws, size_t ws_size,
                              hipStream_t stream) {
  (void)in_sizes; (void)n_in; (void)ws_size;
  const int*   x      = (const int*)d_in[0];
  const float* emb    = (const float*)d_in[1];
  const float* pos    = (const float*)d_in[2];
  const float* wih    = (const float*)d_in[3];
  const float* whh    = (const float*)d_in[4];
  const float* bih    = (const float*)d_in[5];
  const float* bhh    = (const float*)d_in[6];
  const float* lnp_g  = (const float*)d_in[7];
  const float* lnp_b  = (const float*)d_in[8];
  const float* sum_w  = (const float*)d_in[9];
  const float* sum_b  = (const float*)d_in[10];
  const float* msg_w1 = (const float*)d_in[11];
  const float* msg_b1 = (const float*)d_in[12];
  const float* msg_w2 = (const float*)d_in[13];
  const float* msg_b2 = (const float*)d_in[14];
  const float* upd_w1 = (const float*)d_in[15];
  const float* upd_b1 = (const float*)d_in[16];
  const float* upd_w2 = (const float*)d_in[17];
  const float* upd_b2 = (const float*)d_in[18];
  const float* halt_w = (const float*)d_in[19];
  const float* halt_b = (const float*)d_in[20];
  const float* lnm_g  = (const float*)d_in[21];
  const float* lnm_b  = (const float*)d_in[22];
  const float* q_w    = (const float*)d_in[23];
  const float* q_b    = (const float*)d_in[24];
  const float* k_w    = (const float*)d_in[25];
  const float* k_b    = (const float*)d_in[26];
  const float* v_w    = (const float*)d_in[27];
  const float* v_b    = (const float*)d_in[28];
  const float* o_w    = (const float*)d_in[29];
  const float* o_b    = (const float*)d_in[30];
  const float* bc_w   = (const float*)d_in[31];
  const float* bc_b   = (const float*)d_in[32];
  const float* lnf_g  = (const float*)d_in[33];
  const float* lnf_b  = (const float*)d_in[34];
  const float* head_w = (const float*)d_in[35];

  char* base = (char*)d_ws;
  size_t off = 0;
  auto alloc = [&](size_t bytes) -> float* {
    float* p = (float*)(base + off);
    off += (bytes + 255) & ~(size_t)255;
    return p;
  };
  const size_t SL = 16384ull * 256 * 4;  // activation slab (16 MiB)
  float* WIHT  = alloc(768 * 256 * 4);
  float* WHHT  = alloc(768 * 256 * 4);
  float* SUMT  = alloc(256 * 256 * 4);
  float* W1ST  = alloc(256 * 256 * 4);
  float* W1NT  = alloc(256 * 256 * 4);
  float* W2T   = alloc(256 * 256 * 4);
  float* UW1HT = alloc(256 * 256 * 4);
  float* UW1MT = alloc(256 * 256 * 4);
  float* UW2T  = alloc(256 * 256 * 4);
  float* QT    = alloc(256 * 256 * 4);
  float* KT    = alloc(256 * 256 * 4);
  float* VT    = alloc(256 * 256 * 4);
  float* OT    = alloc(256 * 256 * 4);
  float* BCT   = alloc(256 * 256 * 4);
  float* HEADT = alloc(256 * 256 * 4);
  float* XE    = alloc(1024ull * 256 * 4);
  float* GITAB = alloc(1024ull * 768 * 4);
  float* LOC   = alloc(65536ull * 256 * 4);   // gout -> local -> final (in place)
  float* GH    = alloc(16384ull * 768 * 4);   // GRU gates; later overlaid by SCORES
  float* H     = alloc(SL);                   // contiguous after GH: GH+H = 64 MiB
  float* SCORES = GH;                         // [16,1024,1024] f32 overlay
  float* HMP   = alloc(SL);                   // h in MP; later BROAD
  float* ABUF  = alloc(SL);                   // summ_in / a / g ; later Q
  float* BNB   = alloc(SL);                   // bn ; later K
  float* MSGS  = alloc(SL);                   // msgs ; later V
  float* UB    = alloc(SL);                   // update hidden ; later ATT
  float* U2B   = alloc(SL);                   // update out ; later COMB
  float* OUTMP = alloc(SL);
  float* HP    = alloc(256);
  float* out   = (float*)d_out;
  float* klout = out + (out_size - 1);

  // 1) weight transposes
  TransArgs ta;
  ta.d[0]  = { wih,    WIHT,  768, 0,   768 };
  ta.d[1]  = { whh,    WHHT,  768, 0,   768 };
  ta.d[2]  = { sum_w,  SUMT,  256, 0,   256 };
  ta.d[3]  = { msg_w1, W1ST,  256, 0,   256 };
  ta.d[4]  = { msg_w1, W1NT,  256, 256, 256 };
  ta.d[5]  = { msg_w2, W2T,   256, 0,   256 };
  ta.d[6]  = { upd_w1, UW1HT, 256, 0,   256 };
  ta.d[7]  = { upd_w1, UW1MT, 256, 256, 256 };
  ta.d[8]  = { upd_w2, UW2T,  256, 0,   256 };
  ta.d[9]  = { q_w,    QT,    256, 0,   256 };
  ta.d[10] = { k_w,    KT,    256, 0,   256 };
  ta.d[11] = { v_w,    VT,    256, 0,   256 };
  ta.d[12] = { o_w,    OT,    256, 0,   256 };
  ta.d[13] = { bc_w,   BCT,   256, 0,   256 };
  ta.d[14] = { head_w, HEADT, 256, 0,   256 };
  k_transpose<<<dim3(768, 15), 256, 0, stream>>>(ta);

  // 2) GRU input table: gi[p*256+v] = (emb[v]+pos[p]) @ wih + bih
  k_xe<<<1024, 256, 0, stream>>>(emb, pos, XE);
  gemm_nt<GF_BIAS><<<dim3(8, 6, 1), 256, 0, stream>>>(
      XE, WIHT, GITAB, bih, nullptr, 1024, 768, 0, 0, 0, 1.f);

  // 3) GRU over 4 steps
  k_gru_gate<<<16384, 256, 0, stream>>>(x, GITAB, GH, bhh, H, LOC, 0);
  for (int t = 1; t < 4; t++) {
    gemm_nt<GF_BIAS><<<dim3(128, 6, 1), 256, 0, stream>>>(
        H, WHHT, GH, bhh, nullptr, 16384, 768, 0, 0, 0, 1.f);
    k_gru_gate<<<16384, 256, 0, stream>>>(x, GITAB, GH, bhh, H, LOC, t);
  }

  // 4) local = LN(gout) (in place); summaries = mean_t(local) @ sum_w + sum_b
  k_ln<<<65536, 256, 0, stream>>>(LOC, nullptr, 0, LOC, lnp_g, lnp_b);
  k_summ4<<<16384, 256, 0, stream>>>(LOC, ABUF);
  gemm_nt<GF_BIAS><<<dim3(128, 2, 1), 256, 0, stream>>>(
      ABUF, SUMT, HMP, sum_b, nullptr, 16384, 256, 0, 0, 0, 1.f);

  // 5) message-passing rounds
  for (int step = 0; step < 4; step++) {
    gemm_nt<GF_BIAS><<<dim3(128, 2, 1), 256, 0, stream>>>(
        HMP, W1ST, ABUF, msg_b1, nullptr, 16384, 256, 0, 0, 0, 1.f);
    gemm_nt<0><<<dim3(128, 2, 1), 256, 0, stream>>>(
        HMP, W1NT, BNB, nullptr, nullptr, 16384, 256, 0, 0, 0, 1.f);
    k_gelumix<<<16384, 256, 0, stream>>>(ABUF, BNB, ABUF);
    gemm_nt<GF_BIAS><<<dim3(128, 2, 1), 256, 0, stream>>>(
        ABUF, W2T, MSGS, msg_b2, nullptr, 16384, 256, 0, 0, 0, 1.f);
    gemm_nt<GF_BIAS><<<dim3(128, 2, 1), 256, 0, stream>>>(
        HMP, UW1HT, UB, upd_b1, nullptr, 16384, 256, 0, 0, 0, 1.f);
    gemm_nt<GF_ACC | GF_GELU><<<dim3(128, 2, 1), 256, 0, stream>>>(
        MSGS, UW1MT, UB, nullptr, nullptr, 16384, 256, 0, 0, 0, 1.f);
    gemm_nt<GF_BIAS><<<dim3(128, 2, 1), 256, 0, stream>>>(
        UB, UW2T, U2B, upd_b2, nullptr, 16384, 256, 0, 0, 0, 1.f);
    k_ln<<<16384, 256, 0, stream>>>(HMP, U2B, 1, HMP, lnm_g, lnm_b);
    if (step == 2) {
      k_halt<<<16, 256, 0, stream>>>(HMP, halt_w, halt_b, HP);
      k_kl<<<1, 1, 0, stream>>>(HP, klout);
      k_outmp<<<16384, 256, 0, stream>>>(HMP, HP, OUTMP, 0);
    } else if (step == 3) {
      k_outmp<<<16384, 256, 0, stream>>>(HMP, HP, OUTMP, 1);
    }
  }

  // 6) retrieval: q,k,v ; scores ; top-8 softmax-gather ; output proj
  gemm_nt<GF_BIAS><<<dim3(128, 2, 1), 256, 0, stream>>>(
      OUTMP, QT, ABUF, q_b, nullptr, 16384, 256, 0, 0, 0, 1.f);   // Q
  gemm_nt<GF_BIAS><<<dim3(128, 2, 1), 256, 0, stream>>>(
      OUTMP, KT, BNB, k_b, nullptr, 16384, 256, 0, 0, 0, 1.f);    // K
  gemm_nt<GF_BIAS><<<dim3(128, 2, 1), 256, 0, stream>>>(
      OUTMP, VT, MSGS, v_b, nullptr, 16384, 256, 0, 0, 0, 1.f);   // V
  gemm_nt<GF_SCAUSAL><<<dim3(8, 8, 16), 256, 0, stream>>>(
      ABUF, BNB, SCORES, nullptr, nullptr, 1024, 1024,
      262144LL, 262144LL, 1048576LL, 0.0625f);
  k_topk<<<dim3(1024, 16), 64, 0, stream>>>(SCORES, MSGS, UB);    // ATT -> UB
  gemm_nt<GF_BIAS | GF_RES><<<dim3(128, 2, 1), 256, 0, stream>>>(
      UB, OT, U2B, o_b, OUTMP, 16384, 256, 0, 0, 0, 1.f);         // COMB = att@o + b + out_mp
  gemm_nt<GF_BIAS><<<dim3(128, 2, 1), 256, 0, stream>>>(
      U2B, BCT, HMP, bc_b, nullptr, 16384, 256, 0, 0, 0, 1.f);    // BROAD -> HMP

  // 7) final = LN(local + broad) (in place on LOC); logits = final @ head_w
  k_ln<<<65536, 256, 0, stream>>>(LOC, HMP, 2, LOC, lnf_g, lnf_b);
  gemm_nt<0><<<dim3(512, 2, 1), 256, 0, stream>>>(
      LOC, HEADT, out, nullptr, nullptr, 65536, 256, 0, 0, 0, 1.f);
}

// Round 3
// 604.766 us; speedup vs baseline: 1.7533x; 1.7533x over previous
//
#include <hip/hip_runtime.h>
#include <math.h>

// ---------------------------------------------------------------------------
// B=16, T=4096, D=256, V=256, PATCH=4, Np=1024, BN=16384
// All GEMMs: C[M,N] = A[M,256] @ Bt[N,256]^T (+epilogue), bf16 inputs.
// Workspace budget: ~183 MB (R1 proved >=260 MB exists; R2's 283 MB aborted).
// ---------------------------------------------------------------------------

typedef __bf16 bf16_t;
typedef bf16_t bf16x8 __attribute__((ext_vector_type(8)));
typedef bf16_t bf16x4 __attribute__((ext_vector_type(4)));
typedef float f32x4 __attribute__((ext_vector_type(4)));

#define GF_BIAS 1
#define GF_GELU 4
#define GF_RES 8
#define GF_SCAUSAL 16
#define GF_F32OUT 32

__device__ __forceinline__ float gelu_exact(float x) {
  return 0.5f * x * (1.0f + erff(x * 0.7071067811865475f));
}

__device__ __forceinline__ float sigm(float x) { return 1.f / (1.f + expf(-x)); }

__device__ __forceinline__ float wave_sum(float v) {
#pragma unroll
  for (int o = 32; o; o >>= 1) v += __shfl_xor(v, o, 64);
  return v;
}

__device__ __forceinline__ void gload16(const void* g, void* l) {
  __builtin_amdgcn_global_load_lds(
      (const __attribute__((address_space(1))) void*)g,
      (__attribute__((address_space(3))) void*)l, 16, 0, 0);
}

// ---------------- bf16 MFMA GEMM: 128x128 tile, 4 waves, BK=64 --------------
template<int FLAGS>
__global__ __launch_bounds__(256)
void gemm_bt(const bf16_t* __restrict__ A, const bf16_t* __restrict__ Bt,
             void* __restrict__ Cv, const float* __restrict__ bias,
             const bf16_t* __restrict__ res,
             int lda, int ldb, int ldc, int ldr,
             long long sA, long long sB, long long sC, float scale)
{
  __shared__ __align__(16) bf16_t As[128][64];
  __shared__ __align__(16) bf16_t Bs[128][64];
  const int z = blockIdx.z;
  A  += (long long)z * sA;
  Bt += (long long)z * sB;
  const int m0 = blockIdx.x * 128, n0 = blockIdx.y * 128;
  if ((FLAGS & GF_SCAUSAL) && n0 > m0 + 127) return;
  const int tid = threadIdx.x, lane = tid & 63, wave = tid >> 6;
  const int wm = (wave >> 1) << 6, wn = (wave & 1) << 6;
  const int lr = lane & 15, lg = lane >> 4;

  // staging: wave w covers rows [w*32, w*32+32); LDS dest is wave_base+lane*16
  const int srow = wave * 32 + (lane >> 3);
  const int scol = (lane & 7) * 8;
  const bf16_t* ga = A  + (long long)(m0 + srow) * lda + scol;
  const bf16_t* gb = Bt + (long long)(n0 + srow) * ldb + scol;
  char* lA = (char*)(&As[srow][0]) + (lane & 7) * 16;
  char* lB = (char*)(&Bs[srow][0]) + (lane & 7) * 16;

  f32x4 acc[4][4] = {};

#pragma unroll
  for (int kt = 0; kt < 4; kt++) {
    const int ko = kt * 64;
#pragma unroll
    for (int q = 0; q < 4; q++) {
      gload16(ga + (long long)q * 8 * lda + ko, lA + q * 1024);
      gload16(gb + (long long)q * 8 * ldb + ko, lB + q * 1024);
    }
    __syncthreads();
#pragma unroll
    for (int kk = 0; kk < 2; kk++) {
      bf16x8 af[4], bfv[4];
#pragma unroll
      for (int i = 0; i < 4; i++) af[i]  = *(const bf16x8*)&As[wm + i*16 + lr][kk*32 + lg*8];
#pragma unroll
      for (int j = 0; j < 4; j++) bfv[j] = *(const bf16x8*)&Bs[wn + j*16 + lr][kk*32 + lg*8];
#pragma unroll
      for (int i = 0; i < 4; i++)
#pragma unroll
        for (int j = 0; j < 4; j++)
          acc[i][j] = __builtin_amdgcn_mfma_f32_16x16x32_bf16(af[i], bfv[j], acc[i][j], 0, 0, 0);
    }
    if (kt < 3) __syncthreads();
  }

#pragma unroll
  for (int i = 0; i < 4; i++) {
#pragma unroll
    for (int j = 0; j < 4; j++) {
      const int col = n0 + wn + j * 16 + lr;
      const float bval = (FLAGS & GF_BIAS) ? bias[col] : 0.f;
#pragma unroll
      for (int e = 0; e < 4; e++) {
        const int row = m0 + wm + i * 16 + lg * 4 + e;
        float v = acc[i][j][e];
        if (FLAGS & GF_SCAUSAL) { v *= scale; if (col > row) v = -__builtin_inff(); }
        v += bval;
        if (FLAGS & GF_RES) v += (float)res[(long long)row * ldr + col];
        if (FLAGS & GF_GELU) v = gelu_exact(v);
        const long long ci = (long long)z * sC + (long long)row * ldc + col;
        if (FLAGS & GF_F32OUT) ((float*)Cv)[ci] = v;
        else                   ((bf16_t*)Cv)[ci] = (bf16_t)v;
      }
    }
  }
}

// ---------------- prep: weight transposes (f32->bf16), xe, fused biases -----
struct TD { const float* src; bf16_t* dst; int N; int k0; int ld; };
struct PrepArgs {
  TD d[15];
  const float* emb; const float* pos; bf16_t* XE;
  const float* msg_b1; const float* upd_b1;
  const float* q_b; const float* k_b; const float* v_b;
  float* BIAS3; float* QKVB;
};

__global__ __launch_bounds__(256) void k_prep(PrepArgs pa) {
  const int y = blockIdx.y, x = blockIdx.x, d = threadIdx.x;
  if (y < 15) {
    TD t = pa.d[y];
    if (x >= t.N) return;
    t.dst[(long long)x * 256 + d] = (bf16_t)t.src[(long long)(t.k0 + d) * t.ld + x];
  } else if (y == 15) {
    const int p = x >> 8, v = x & 255;
    pa.XE[(long long)x * 256 + d] = (bf16_t)(pa.emb[v * 256 + d] + pa.pos[p * 256 + d]);
  } else {
    if      (x == 0) pa.BIAS3[d] = pa.msg_b1[d];
    else if (x == 1) pa.BIAS3[256 + d] = 0.f;
    else if (x == 2) pa.BIAS3[512 + d] = pa.upd_b1[d];
    else if (x == 3) pa.QKVB[d] = pa.q_b[d];
    else if (x == 4) pa.QKVB[256 + d] = pa.k_b[d];
    else if (x == 5) pa.QKVB[512 + d] = pa.v_b[d];
  }
}

// ---------------- GRU gate ---------------------------------------------------
__global__ __launch_bounds__(64)
void k_gru_gate(const int* __restrict__ x, const float* __restrict__ gitab,
                const bf16_t* __restrict__ GH, const float* __restrict__ bhh,
                bf16_t* __restrict__ H, bf16_t* __restrict__ LOC, int t)
{
  const int s = blockIdx.x, lane = threadIdx.x, d0 = lane * 4;
  const int v = x[s * 4 + t];
  const float* gi = gitab + (long long)(t * 256 + v) * 768;
  const float4 i_r = *(const float4*)(gi + d0);
  const float4 i_z = *(const float4*)(gi + 256 + d0);
  const float4 i_n = *(const float4*)(gi + 512 + d0);
  const float ir[4] = {i_r.x, i_r.y, i_r.z, i_r.w};
  const float iz[4] = {i_z.x, i_z.y, i_z.z, i_z.w};
  const float in_[4] = {i_n.x, i_n.y, i_n.z, i_n.w};
  float hr[4], hz[4], hn[4], hp[4];
  if (t == 0) {
#pragma unroll
    for (int e = 0; e < 4; e++) {
      hr[e] = bhh[d0 + e]; hz[e] = bhh[256 + d0 + e]; hn[e] = bhh[512 + d0 + e];
      hp[e] = 0.f;
    }
  } else {
    const bf16_t* gh = GH + (long long)s * 768;
    const bf16x4 a = *(const bf16x4*)(gh + d0);
    const bf16x4 b4 = *(const bf16x4*)(gh + 256 + d0);
    const bf16x4 c4 = *(const bf16x4*)(gh + 512 + d0);
    const bf16x4 hv = *(const bf16x4*)(H + (long long)s * 256 + d0);
#pragma unroll
    for (int e = 0; e < 4; e++) { hr[e] = a[e]; hz[e] = b4[e]; hn[e] = c4[e]; hp[e] = hv[e]; }
  }
  bf16x4 ho;
#pragma unroll
  for (int e = 0; e < 4; e++) {
    const float r = sigm(ir[e] + hr[e]);
    const float zz = sigm(iz[e] + hz[e]);
    const float nn = tanhf(in_[e] + r * hn[e]);
    ho[e] = (bf16_t)((1.f - zz) * nn + zz * hp[e]);
  }
  *(bf16x4*)(H + (long long)s * 256 + d0) = ho;
  *(bf16x4*)(LOC + ((long long)s * 4 + t) * 256 + d0) = ho;
}

// ---------------- LN (generic, 64 threads/row) ------------------------------
// addmode: 0 none, 1 add same-row, 2 add row>>2
__global__ __launch_bounds__(64)
void k_ln(const bf16_t* __restrict__ X, const bf16_t* __restrict__ ADD, int addmode,
          bf16_t* __restrict__ OUT, const float* __restrict__ g,
          const float* __restrict__ b)
{
  const long long r = blockIdx.x;
  const int d0 = threadIdx.x * 4;
  const bf16x4 xv = *(const bf16x4*)(X + r * 256 + d0);
  float xf[4];
#pragma unroll
  for (int e = 0; e < 4; e++) xf[e] = (float)xv[e];
  if (addmode == 1) {
    const bf16x4 av = *(const bf16x4*)(ADD + r * 256 + d0);
#pragma unroll
    for (int e = 0; e < 4; e++) xf[e] += (float)av[e];
  } else if (addmode == 2) {
    const bf16x4 av = *(const bf16x4*)(ADD + (r >> 2) * 256 + d0);
#pragma unroll
    for (int e = 0; e < 4; e++) xf[e] += (float)av[e];
  }
  const float mean = wave_sum(xf[0] + xf[1] + xf[2] + xf[3]) * (1.f / 256.f);
  float q = 0.f;
#pragma unroll
  for (int e = 0; e < 4; e++) { const float dx = xf[e] - mean; q += dx * dx; }
  const float rstd = rsqrtf(wave_sum(q) * (1.f / 256.f) + 1e-5f);
  const float4 gv = *(const float4*)(g + d0);
  const float4 bv = *(const float4*)(b + d0);
  const float gg[4] = {gv.x, gv.y, gv.z, gv.w};
  const float bb[4] = {bv.x, bv.y, bv.z, bv.w};
  bf16x4 ov;
#pragma unroll
  for (int e = 0; e < 4; e++) ov[e] = (bf16_t)((xf[e] - mean) * rstd * gg[e] + bb[e]);
  *(bf16x4*)(OUT + r * 256 + d0) = ov;
}

// ---------------- fused patch-LN + mean over 4 rows -------------------------
__global__ __launch_bounds__(64)
void k_lnp4(bf16_t* __restrict__ LOC, bf16_t* __restrict__ SUMB,
            const float* __restrict__ g, const float* __restrict__ b)
{
  const long long s = blockIdx.x;
  const int d0 = threadIdx.x * 4;
  const float4 gv = *(const float4*)(g + d0);
  const float4 bv = *(const float4*)(b + d0);
  const float gg[4] = {gv.x, gv.y, gv.z, gv.w};
  const float bb[4] = {bv.x, bv.y, bv.z, bv.w};
  float accd[4] = {0.f, 0.f, 0.f, 0.f};
#pragma unroll
  for (int t = 0; t < 4; t++) {
    bf16_t* row = LOC + (s * 4 + t) * 256 + d0;
    const bf16x4 xv = *(const bf16x4*)row;
    float xf[4];
#pragma unroll
    for (int e = 0; e < 4; e++) xf[e] = (float)xv[e];
    const float mean = wave_sum(xf[0] + xf[1] + xf[2] + xf[3]) * (1.f / 256.f);
    float q = 0.f;
#pragma unroll
    for (int e = 0; e < 4; e++) { const float dx = xf[e] - mean; q += dx * dx; }
    const float rstd = rsqrtf(wave_sum(q) * (1.f / 256.f) + 1e-5f);
    bf16x4 ov;
#pragma unroll
    for (int e = 0; e < 4; e++) {
      const float y = (xf[e] - mean) * rstd * gg[e] + bb[e];
      ov[e] = (bf16_t)y;
      accd[e] += y;
    }
    *(bf16x4*)row = ov;
  }
  bf16x4 sv;
#pragma unroll
  for (int e = 0; e < 4; e++) sv[e] = (bf16_t)(accd[e] * 0.25f);
  *(bf16x4*)(SUMB + s * 256 + d0) = sv;
}

// ---------------- gelu-mix over window (reads fused A3) ---------------------
// G[s][d] = (1/5) sum_{w=0..4} gelu(a[s][d] + (n>=w ? bn[s-w][d] : 0))
__global__ __launch_bounds__(64)
void k_gelumix(const bf16_t* __restrict__ A3, bf16_t* __restrict__ G)
{
  const long long s = blockIdx.x;
  const int n = (int)(s & 1023);
  const int d0 = threadIdx.x * 4;
  const bf16x4 av = *(const bf16x4*)(A3 + s * 768 + d0);
  float a[4];
#pragma unroll
  for (int e = 0; e < 4; e++) a[e] = (float)av[e];
  float acc[4] = {0.f, 0.f, 0.f, 0.f};
  const bf16_t* bbase = A3 + s * 768 + 256 + d0;
#pragma unroll
  for (int w = 0; w <= 4; w++) {
    if (n >= w) {
      const bf16x4 bn = *(const bf16x4*)(bbase - (long long)w * 768);
#pragma unroll
      for (int e = 0; e < 4; e++) acc[e] += gelu_exact(a[e] + (float)bn[e]);
    } else {
#pragma unroll
      for (int e = 0; e < 4; e++) acc[e] += gelu_exact(a[e]);
    }
  }
  bf16x4 ov;
#pragma unroll
  for (int e = 0; e < 4; e++) ov[e] = (bf16_t)(acc[e] * 0.2f);
  *(bf16x4*)(G + s * 256 + d0) = ov;
}

// ---------------- halting ----------------------------------------------------
__global__ __launch_bounds__(64)
void k_halt1(const bf16_t* __restrict__ Hm, float* __restrict__ PS) {
  const int c = blockIdx.x, b = blockIdx.y, d0 = threadIdx.x * 4;
  float acc[4] = {0.f, 0.f, 0.f, 0.f};
  const bf16_t* base = Hm + ((long long)b * 1024 + c * 32) * 256 + d0;
#pragma unroll 4
  for (int n = 0; n < 32; n++) {
    const bf16x4 hv = *(const bf16x4*)(base + (long long)n * 256);
#pragma unroll
    for (int e = 0; e < 4; e++) acc[e] += (float)hv[e];
  }
  float4 o4; o4.x = acc[0]; o4.y = acc[1]; o4.z = acc[2]; o4.w = acc[3];
  *(float4*)(PS + ((long long)b * 32 + c) * 256 + d0) = o4;
}

__global__ __launch_bounds__(64)
void k_halt2(const float* __restrict__ PS, const float* __restrict__ hw,
             const float* __restrict__ hb, float* __restrict__ HP) {
  const int b = blockIdx.x, d0 = threadIdx.x * 4;
  float acc[4] = {0.f, 0.f, 0.f, 0.f};
  for (int c = 0; c < 32; c++) {
    const float4 p4 = *(const float4*)(PS + ((long long)b * 32 + c) * 256 + d0);
    acc[0] += p4.x; acc[1] += p4.y; acc[2] += p4.z; acc[3] += p4.w;
  }
  const float4 w4 = *(const float4*)(hw + d0);
  float val = (acc[0] * w4.x + acc[1] * w4.y + acc[2] * w4.z + acc[3] * w4.w) * (1.f / 1024.f);
  val = wave_sum(val);
  if (threadIdx.x == 0) HP[b] = sigm(val + hb[0]);
}

__global__ void k_kl(const float* __restrict__ HP, float* __restrict__ out) {
  float s = 0.f;
  for (int b = 0; b < 16; b++) s += HP[b];
  const float hpm = s * (1.f / 16.f);
  const float l8 = logf(1e-8f);
  const float p0 = 0.2f, p1 = 0.16f, p2 = 0.128f, p3 = 0.1024f;
  const float kl = p0 * (logf(p0) - l8)
                 + p1 * (logf(p1) - l8)
                 + p2 * (logf(p2) - logf(hpm + 1e-8f))
                 + p3 * (logf(p3) - logf(1.f + 1e-8f));
  out[0] = kl * 0.25f;
}

// out_mp: acc=0 -> O = hp[b]*h ; acc=1 -> O += (1-hp[b])*h
__global__ __launch_bounds__(64)
void k_outmp(const bf16_t* __restrict__ Hm, const float* __restrict__ HP,
             bf16_t* __restrict__ O, int acc) {
  const long long s = blockIdx.x;
  const int d0 = threadIdx.x * 4;
  const int b = (int)(s >> 10);
  const float hp = HP[b];
  const bf16x4 hv = *(const bf16x4*)(Hm + s * 256 + d0);
  bf16x4 ov;
  if (acc) {
    const bf16x4 pv = *(const bf16x4*)(O + s * 256 + d0);
#pragma unroll
    for (int e = 0; e < 4; e++) ov[e] = (bf16_t)((float)pv[e] + (1.f - hp) * (float)hv[e]);
  } else {
#pragma unroll
    for (int e = 0; e < 4; e++) ov[e] = (bf16_t)(hp * (float)hv[e]);
  }
  *(bf16x4*)(O + s * 256 + d0) = ov;
}

// ---------------- top-8 causal sparse attention (4 rows / 256-thr block) ----
__global__ __launch_bounds__(256)
void k_topk(const float* __restrict__ S, const bf16_t* __restrict__ QKV,
            bf16_t* __restrict__ O) {
  const int n = blockIdx.x * 4 + (threadIdx.x >> 6);
  const int b = blockIdx.y;
  const int lane = threadIdx.x & 63;
  const float* srow = S + ((long long)b * 1024 + n) * 1024;
  float tv[8]; int ti[8];
#pragma unroll
  for (int j = 0; j < 8; j++) { tv[j] = -__builtin_inff(); ti[j] = 0x7fffffff; }
  for (int mb = lane * 4; mb <= n; mb += 256) {
    const float4 s4 = *(const float4*)(srow + mb);
    const float sv[4] = {s4.x, s4.y, s4.z, s4.w};
#pragma unroll
    for (int jj = 0; jj < 4; jj++) {
      const int m = mb + jj;
      if (m <= n) {
        const float s = sv[jj];
        if (s > tv[7] || (s == tv[7] && m < ti[7])) {
          tv[7] = s; ti[7] = m;
#pragma unroll
          for (int j = 7; j > 0; j--) {
            const bool sw = (tv[j] > tv[j-1]) || (tv[j] == tv[j-1] && ti[j] < ti[j-1]);
            if (sw) {
              const float tf = tv[j]; tv[j] = tv[j-1]; tv[j-1] = tf;
              const int   tt = ti[j]; ti[j] = ti[j-1]; ti[j-1] = tt;
            }
          }
        }
      }
    }
  }
  float outv[8]; int outi[8];
#pragma unroll
  for (int r = 0; r < 8; r++) {
    float bv = tv[0]; int bi = ti[0]; int bl = lane;
    for (int off = 32; off; off >>= 1) {
      const float ov = __shfl_xor(bv, off, 64);
      const int   oi = __shfl_xor(bi, off, 64);
      const int   ol = __shfl_xor(bl, off, 64);
      if (ov > bv || (ov == bv && oi < bi)) { bv = ov; bi = oi; bl = ol; }
    }
    outv[r] = bv; outi[r] = bi;
    if (lane == bl) {
      tv[0]=tv[1]; ti[0]=ti[1]; tv[1]=tv[2]; ti[1]=ti[2]; tv[2]=tv[3]; ti[2]=ti[3];
      tv[3]=tv[4]; ti[3]=ti[4]; tv[4]=tv[5]; ti[4]=ti[5]; tv[5]=tv[6]; ti[5]=ti[6];
      tv[6]=tv[7]; ti[6]=ti[7]; tv[7] = -__builtin_inff(); ti[7] = 0x7fffffff;
    }
  }
  const float mx = outv[0];
  float w[8]; float den = 0.f;
#pragma unroll
  for (int j = 0; j < 8; j++) {
    w[j] = (outv[j] > -__builtin_inff()) ? expf(outv[j] - mx) : 0.f;
    den += w[j];
  }
  const float inv = 1.f / den;
  float a[4] = {0.f, 0.f, 0.f, 0.f};
#pragma unroll
  for (int j = 0; j < 8; j++) {
    if (outv[j] > -__builtin_inff()) {
      const bf16x4 vv = *(const bf16x4*)(QKV + ((long long)b * 1024 + outi[j]) * 768 + 512 + lane * 4);
      const float wj = w[j] * inv;
#pragma unroll
      for (int e = 0; e < 4; e++) a[e] = fmaf(wj, (float)vv[e], a[e]);
    }
  }
  bf16x4 o4;
#pragma unroll
  for (int e = 0; e < 4; e++) o4[e] = (bf16_t)a[e];
  *(bf16x4*)(O + ((long long)b * 1024 + n) * 256 + lane * 4) = o4;
}

// ---------------------------------------------------------------------------
extern "C" void kernel_launch(void* const* d_in, const int* in_sizes, int n_in,
                              void* d_out, int out_size, void* d_ws, size_t ws_size,
                              hipStream_t stream) {
  (void)in_sizes; (void)n_in; (void)ws_size;
  const int*   x      = (const int*)d_in[0];
  const float* emb    = (const float*)d_in[1];
  const float* pos    = (const float*)d_in[2];
  const float* wih    = (const float*)d_in[3];
  const float* whh    = (const float*)d_in[4];
  const float* bih    = (const float*)d_in[5];
  const float* bhh    = (const float*)d_in[6];
  const float* lnp_g  = (const float*)d_in[7];
  const float* lnp_b  = (const float*)d_in[8];
  const float* sum_w  = (const float*)d_in[9];
  const float* sum_b  = (const float*)d_in[10];
  const float* msg_w1 = (const float*)d_in[11];
  const float* msg_b1 = (const float*)d_in[12];
  const float* msg_w2 = (const float*)d_in[13];
  const float* msg_b2 = (const float*)d_in[14];
  const float* upd_w1 = (const float*)d_in[15];
  const float* upd_b1 = (const float*)d_in[16];
  const float* upd_w2 = (const float*)d_in[17];
  const float* upd_b2 = (const float*)d_in[18];
  const float* halt_w = (const float*)d_in[19];
  const float* halt_b = (const float*)d_in[20];
  const float* lnm_g  = (const float*)d_in[21];
  const float* lnm_b  = (const float*)d_in[22];
  const float* q_b    = (const float*)d_in[24];
  const float* k_b    = (const float*)d_in[26];
  const float* v_b    = (const float*)d_in[28];
  const float* o_b    = (const float*)d_in[30];
  const float* bc_b   = (const float*)d_in[32];
  const float* lnf_g  = (const float*)d_in[33];
  const float* lnf_b  = (const float*)d_in[34];
  // weights: q_w=23, k_w=25, v_w=27, o_w=29, bc_w=31, head_w=35

  char* base = (char*)d_ws;
  size_t off = 0;
  auto alloc = [&](size_t bytes) -> void* {
    void* p = (void*)(base + off);
    off += (bytes + 255) & ~(size_t)255;
    return p;
  };
  const size_t SL2 = 16384ull * 256 * 2;   // bf16 activation slab (8 MiB)
  bf16_t* WIHT  = (bf16_t*)alloc(768 * 256 * 2);
  bf16_t* WHHT  = (bf16_t*)alloc(768 * 256 * 2);
  bf16_t* SUMT  = (bf16_t*)alloc(256 * 256 * 2);
  bf16_t* MW    = (bf16_t*)alloc(768 * 256 * 2);   // [msgW1self; msgW1neigh; updW1h]
  bf16_t* W2T   = (bf16_t*)alloc(256 * 256 * 2);
  bf16_t* UW1MT = (bf16_t*)alloc(256 * 256 * 2);
  bf16_t* UW2T  = (bf16_t*)alloc(256 * 256 * 2);
  bf16_t* QKVW  = (bf16_t*)alloc(768 * 256 * 2);
  bf16_t* OT    = (bf16_t*)alloc(256 * 256 * 2);
  bf16_t* BCT   = (bf16_t*)alloc(256 * 256 * 2);
  bf16_t* HEADT = (bf16_t*)alloc(256 * 256 * 2);
  float*  BIAS3 = (float*)alloc(768 * 4);
  float*  QKVB  = (float*)alloc(768 * 4);
  bf16_t* XE    = (bf16_t*)alloc(1024ull * 256 * 2);
  float*  GITAB = (float*)alloc(1024ull * 768 * 4);
  bf16_t* LOCb  = (bf16_t*)alloc(65536ull * 256 * 2);        // 32 MiB

  // --- 64 MiB overlay region: SCORES (phase D) over GH/H/SUMB/A3 (A/B/C) ---
  char*   SCR   = (char*)alloc(16ull * 1024 * 1024 * 4);     // 64 MiB
  float*  SCORES = (float*)SCR;
  bf16_t* GH    = (bf16_t*)SCR;                              // 24 MiB (GRU)
  bf16_t* H     = (bf16_t*)(SCR + 25165824);                 //  8 MiB (GRU)
  bf16_t* SUMB  = (bf16_t*)(SCR + 33554432);                 //  8 MiB (phase B)
  bf16_t* A3    = (bf16_t*)(SCR + 41943040);                 // 24 MiB (MP rounds)

  bf16_t* HMP   = (bf16_t*)alloc(SL2);
  bf16_t* G     = (bf16_t*)alloc(SL2);
  bf16_t* MSGS  = (bf16_t*)alloc(SL2);   // later BROAD
  bf16_t* UB    = (bf16_t*)alloc(SL2);   // later ATT
  bf16_t* U2B   = (bf16_t*)alloc(SL2);   // later COMB
  bf16_t* OUTMP = (bf16_t*)alloc(SL2);
  bf16_t* QKV   = (bf16_t*)alloc(16384ull * 768 * 2);        // 24 MiB
  float*  PS    = (float*)alloc(512ull * 256 * 4);
  float*  HP    = (float*)alloc(64);
  bf16_t* ATT   = UB;
  bf16_t* COMB  = U2B;
  bf16_t* BROAD = MSGS;
  float*  out   = (float*)d_out;
  float*  klout = out + (out_size - 1);

  // 1) prep: transposes + xe + fused biases, one launch
  PrepArgs pa;
  pa.d[0]  = { wih,                    WIHT,            768, 0,   768 };
  pa.d[1]  = { whh,                    WHHT,            768, 0,   768 };
  pa.d[2]  = { sum_w,                  SUMT,            256, 0,   256 };
  pa.d[3]  = { msg_w1,                 MW,              256, 0,   256 };
  pa.d[4]  = { msg_w1,                 MW + 256 * 256,  256, 256, 256 };
  pa.d[5]  = { upd_w1,                 MW + 512 * 256,  256, 0,   256 };
  pa.d[6]  = { msg_w2,                 W2T,             256, 0,   256 };
  pa.d[7]  = { upd_w1,                 UW1MT,           256, 256, 256 };
  pa.d[8]  = { upd_w2,                 UW2T,            256, 0,   256 };
  pa.d[9]  = { (const float*)d_in[23], QKVW,            256, 0,   256 };
  pa.d[10] = { (const float*)d_in[25], QKVW + 256*256,  256, 0,   256 };
  pa.d[11] = { (const float*)d_in[27], QKVW + 512*256,  256, 0,   256 };
  pa.d[12] = { (const float*)d_in[29], OT,              256, 0,   256 };
  pa.d[13] = { (const float*)d_in[31], BCT,             256, 0,   256 };
  pa.d[14] = { (const float*)d_in[35], HEADT,           256, 0,   256 };
  pa.emb = emb; pa.pos = pos; pa.XE = XE;
  pa.msg_b1 = msg_b1; pa.upd_b1 = upd_b1;
  pa.q_b = q_b; pa.k_b = k_b; pa.v_b = v_b;
  pa.BIAS3 = BIAS3; pa.QKVB = QKVB;
  k_prep<<<dim3(1024, 17), 256, 0, stream>>>(pa);

  // 2) GRU input table (f32 out): gi = (emb+pos) @ wih + bih
  gemm_bt<GF_BIAS | GF_F32OUT><<<dim3(8, 6, 1), 256, 0, stream>>>(
      XE, WIHT, GITAB, bih, nullptr, 256, 256, 768, 0, 0, 0, 0, 1.f);

  // 3) GRU over 4 steps
  k_gru_gate<<<16384, 64, 0, stream>>>(x, GITAB, GH, bhh, H, LOCb, 0);
  for (int t = 1; t < 4; t++) {
    gemm_bt<GF_BIAS><<<dim3(128, 6, 1), 256, 0, stream>>>(
        H, WHHT, GH, bhh, nullptr, 256, 256, 768, 0, 0, 0, 0, 1.f);
    k_gru_gate<<<16384, 64, 0, stream>>>(x, GITAB, GH, bhh, H, LOCb, t);
  }

  // 4) local = LN(gout) in place + patch means; summaries GEMM
  k_lnp4<<<16384, 64, 0, stream>>>(LOCb, SUMB, lnp_g, lnp_b);
  gemm_bt<GF_BIAS><<<dim3(128, 2, 1), 256, 0, stream>>>(
      SUMB, SUMT, HMP, sum_b, nullptr, 256, 256, 256, 0, 0, 0, 0, 1.f);

  // 5) message-passing rounds
  for (int step = 0; step < 4; step++) {
    gemm_bt<GF_BIAS><<<dim3(128, 6, 1), 256, 0, stream>>>(
        HMP, MW, A3, BIAS3, nullptr, 256, 256, 768, 0, 0, 0, 0, 1.f);
    k_gelumix<<<16384, 64, 0, stream>>>(A3, G);
    gemm_bt<GF_BIAS><<<dim3(128, 2, 1), 256, 0, stream>>>(
        G, W2T, MSGS, msg_b2, nullptr, 256, 256, 256, 0, 0, 0, 0, 1.f);
    gemm_bt<GF_RES | GF_GELU><<<dim3(128, 2, 1), 256, 0, stream>>>(
        MSGS, UW1MT, UB, nullptr, A3 + 512, 256, 256, 256, 768, 0, 0, 0, 1.f);
    gemm_bt<GF_BIAS><<<dim3(128, 2, 1), 256, 0, stream>>>(
        UB, UW2T, U2B, upd_b2, nullptr, 256, 256, 256, 0, 0, 0, 0, 1.f);
    k_ln<<<16384, 64, 0, stream>>>(HMP, U2B, 1, HMP, lnm_g, lnm_b);
    if (step == 2) {
      k_halt1<<<dim3(32, 16), 64, 0, stream>>>(HMP, PS);
      k_halt2<<<16, 64, 0, stream>>>(PS, halt_w, halt_b, HP);
      k_kl<<<1, 1, 0, stream>>>(HP, klout);
      k_outmp<<<16384, 64, 0, stream>>>(HMP, HP, OUTMP, 0);
    } else if (step == 3) {
      k_outmp<<<16384, 64, 0, stream>>>(HMP, HP, OUTMP, 1);
    }
  }

  // 6) retrieval (GH/H/SUMB/A3 all dead -> SCORES may use the overlay region)
  gemm_bt<GF_BIAS><<<dim3(128, 6, 1), 256, 0, stream>>>(
      OUTMP, QKVW, QKV, QKVB, nullptr, 256, 256, 768, 0, 0, 0, 0, 1.f);
  gemm_bt<GF_SCAUSAL | GF_F32OUT><<<dim3(8, 8, 16), 256, 0, stream>>>(
      QKV, QKV + 256, SCORES, nullptr, nullptr, 768, 768, 1024, 0,
      1024LL * 768, 1024LL * 768, 1024LL * 1024, 0.0625f);
  k_topk<<<dim3(256, 16), 256, 0, stream>>>(SCORES, QKV, ATT);
  gemm_bt<GF_BIAS | GF_RES><<<dim3(128, 2, 1), 256, 0, stream>>>(
      ATT, OT, COMB, o_b, OUTMP, 256, 256, 256, 256, 0, 0, 0, 1.f);
  gemm_bt<GF_BIAS><<<dim3(128, 2, 1), 256, 0, stream>>>(
      COMB, BCT, BROAD, bc_b, nullptr, 256, 256, 256, 0, 0, 0, 0, 1.f);

  // 7) final = LN(local + broad) in place; logits = final @ head_w (f32 out)
  k_ln<<<65536, 64, 0, stream>>>(LOCb, BROAD, 2, LOCb, lnf_g, lnf_b);
  gemm_bt<GF_F32OUT><<<dim3(512, 2, 1), 256, 0, stream>>>(
      LOCb, HEADT, out, nullptr, nullptr, 256, 256, 256, 0, 0, 0, 0, 1.f);
}